// Round 4
// baseline (1791.970 us; speedup 1.0000x reference)
//
#include <hip/hip_runtime.h>
#include <math.h>

// SPDNet collapse: both ReEig clamps are inactive (lambda_min >= 1e-3 > 1e-4 by
// construction), so:  out = vec(logm(V^T x V)) @ w_lin^T + b_lin,  V = w1@w2.
// One thread per matrix; 11x11 Jacobi fully unrolled in registers.
//
// R4: occupancy 1->2 waves/EU.
//  - prep kernel writes V / b_lin / symmetrized-Ws into d_ws; main-kernel
//    epilogue reads Ws via wave-uniform global loads (scalar cache), removing
//    ~900 ds_read_b128/thread and 14.8 KB LDS.
//  - L-reconstruction retires U rows progressively (peak 217 -> ~155 regs), so
//    the kernel-wide peak (~200, Jacobi) fits the 256-reg budget of 2 waves/EU.
//  - amdgpu_waves_per_eu(2,2) forces the RA to the 256 cap.

#define NSWEEP 7

// d_ws float layout: [0..143] V (12x12, col 11 zero) | [160..211] b_lin |
//                    [256..256+52*68) Ws_sym rows padded to 68
#define WS_V 0
#define WS_B 160
#define WS_W 256

__device__ __forceinline__ constexpr int UT(int i, int j) { // i<=j, n=11 upper tri
  return i * 11 - (i * (i - 1)) / 2 + (j - i);
}

template <int P, int Q>
__device__ __forceinline__ void jrot(float (&M)[66], float (&U)[121]) {
  const float app = M[UT(P, P)];
  const float aqq = M[UT(Q, Q)];
  const float apq = M[UT(P, Q)];
  const bool tiny = __builtin_fabsf(apq) < 1e-30f;
  const float apqs = tiny ? 1.0f : apq;
  float tau = (aqq - app) * 0.5f * __builtin_amdgcn_rcpf(apqs);
  float t = __builtin_amdgcn_rcpf(__builtin_fabsf(tau) +
                                  __builtin_amdgcn_sqrtf(__builtin_fmaf(tau, tau, 1.0f)));
  t = __builtin_copysignf(t, tau);
  float c = __builtin_amdgcn_rsqf(__builtin_fmaf(t, t, 1.0f));
  float s = t * c;
  c = tiny ? 1.0f : c;
  s = tiny ? 0.0f : s;
#pragma unroll
  for (int k = 0; k < 11; ++k) {
    if (k == P || k == Q) continue;
    const int ikp = (k < P) ? UT(k, P) : UT(P, k);
    const int ikq = (k < Q) ? UT(k, Q) : UT(Q, k);
    const float akp = M[ikp], akq = M[ikq];
    M[ikp] = __builtin_fmaf(c, akp, -s * akq);
    M[ikq] = __builtin_fmaf(s, akp, c * akq);
  }
  const float cc = c * c, ss = s * s, cs2 = 2.0f * c * s * apq;
  M[UT(P, P)] = cc * app - cs2 + ss * aqq;
  M[UT(Q, Q)] = ss * app + cs2 + cc * aqq;
  M[UT(P, Q)] = 0.0f;
#pragma unroll
  for (int k = 0; k < 11; ++k) {
    const float ukp = U[k * 11 + P], ukq = U[k * 11 + Q];
    U[k * 11 + P] = __builtin_fmaf(c, ukp, -s * ukq);
    U[k * 11 + Q] = __builtin_fmaf(s, ukp, c * ukq);
  }
}

// Round-robin sweep: round R pairs { ((R+K)%11,(R+11-K)%11) }, K=1..5 ->
// 5 disjoint pairs/round, 11 rounds cover all 55 pairs exactly once.
template <int R, int K>
struct SweepRR {
  static constexpr int A0 = (R + K) % 11;
  static constexpr int B0 = (R + 11 - K) % 11;
  static constexpr int P = A0 < B0 ? A0 : B0;
  static constexpr int Q = A0 < B0 ? B0 : A0;
  static __device__ __forceinline__ void run(float (&M)[66], float (&U)[121]) {
    jrot<P, Q>(M, U);
    if constexpr (K < 5)
      SweepRR<R, K + 1>::run(M, U);
    else if constexpr (R < 10)
      SweepRR<R + 1, 1>::run(M, U);
  }
};

__global__ __launch_bounds__(256) void prep_kernel(
    const float* __restrict__ w1, const float* __restrict__ w2,
    const float* __restrict__ wlin, const float* __restrict__ blin,
    float* __restrict__ ws) {
  const int g = blockIdx.x * 256 + threadIdx.x;
  const int gs = gridDim.x * 256;
  for (int idx = g; idx < 144; idx += gs) {
    const int i = idx / 12, l = idx % 12;
    float acc = 0.f;
    if (l < 11) {
#pragma unroll
      for (int j = 0; j < 12; ++j) acc = __builtin_fmaf(w1[i * 12 + j], w2[j * 11 + l], acc);
    }
    ws[WS_V + idx] = acc;
  }
  for (int idx = g; idx < 52; idx += gs) ws[WS_B + idx] = blin[idx];
  for (int idx = g; idx < 52 * 68; idx += gs) {
    const int c = idx / 68, t = idx % 68;
    float v = 0.f;
    if (t < 66) {
      int i = 0, rem = t;
      while (rem >= 11 - i) { rem -= 11 - i; ++i; }
      const int j = i + rem;
      v = wlin[c * 121 + i * 11 + j];
      if (i != j) v += wlin[c * 121 + j * 11 + i];
    }
    ws[WS_W + idx] = v;
  }
}

__global__ __attribute__((amdgpu_flat_work_group_size(256, 256)))
__attribute__((amdgpu_waves_per_eu(2, 2)))
void manifold_kernel(const float* __restrict__ x, const float* __restrict__ ws,
                     float* __restrict__ out, int B) {
  __shared__ __align__(16) float sV[12 * 12];
  const int tid = threadIdx.x;
  if (tid < 36) {
    reinterpret_cast<float4*>(sV)[tid] =
        reinterpret_cast<const float4*>(ws + WS_V)[tid];
  }
  __syncthreads();

  const int b = blockIdx.x * 256 + tid;
  if (b >= B) return;

  // ---- Pass 1: T = V^T X (11x12), X streamed by row, V rows from LDS ----
  float T[132];
#pragma unroll
  for (int e = 0; e < 132; ++e) T[e] = 0.f;
  const float4* xb4 = reinterpret_cast<const float4*>(x + (size_t)b * 144);
#pragma unroll 1
  for (int i = 0; i < 12; ++i) {
    const float4 a0 = xb4[i * 3 + 0], a1 = xb4[i * 3 + 1], a2 = xb4[i * 3 + 2];
    const float xr[12] = {a0.x, a0.y, a0.z, a0.w, a1.x, a1.y, a1.z, a1.w,
                          a2.x, a2.y, a2.z, a2.w};
    const float4 v0 = *reinterpret_cast<const float4*>(&sV[i * 12 + 0]);
    const float4 v1 = *reinterpret_cast<const float4*>(&sV[i * 12 + 4]);
    const float4 v2 = *reinterpret_cast<const float4*>(&sV[i * 12 + 8]);
    const float vr[11] = {v0.x, v0.y, v0.z, v0.w, v1.x, v1.y, v1.z, v1.w,
                          v2.x, v2.y, v2.z};
#pragma unroll
    for (int k = 0; k < 11; ++k)
#pragma unroll
      for (int j = 0; j < 12; ++j)
        T[k * 12 + j] = __builtin_fmaf(vr[k], xr[j], T[k * 12 + j]);
  }

  // ---- Pass 2: M = T V (upper triangle), V rows from LDS ----
  float M[66];
#pragma unroll
  for (int e = 0; e < 66; ++e) M[e] = 0.f;
#pragma unroll 1
  for (int j = 0; j < 12; ++j) {
    const float4 v0 = *reinterpret_cast<const float4*>(&sV[j * 12 + 0]);
    const float4 v1 = *reinterpret_cast<const float4*>(&sV[j * 12 + 4]);
    const float4 v2 = *reinterpret_cast<const float4*>(&sV[j * 12 + 8]);
    const float vr[11] = {v0.x, v0.y, v0.z, v0.w, v1.x, v1.y, v1.z, v1.w,
                          v2.x, v2.y, v2.z};
#pragma unroll
    for (int k = 0; k < 11; ++k) {
      const float tkj = T[k * 12 + j];
#pragma unroll
      for (int l = k; l < 11; ++l)
        M[UT(k, l)] = __builtin_fmaf(tkj, vr[l], M[UT(k, l)]);
    }
  }

  // ---- Jacobi eigendecomposition (T dead from here) ----
  float U[121];
#pragma unroll
  for (int e = 0; e < 121; ++e) U[e] = 0.f;
#pragma unroll
  for (int d = 0; d < 11; ++d) U[d * 11 + d] = 1.f;
#pragma unroll 1
  for (int sweep = 0; sweep < NSWEEP; ++sweep) {
    SweepRR<0, 1>::run(M, U);
  }

  // ---- eigen-log (clamp matches the reference's preceding ReEig) ----
  float lw[11];
#pragma unroll
  for (int k = 0; k < 11; ++k) lw[k] = __logf(fmaxf(M[UT(k, k)], 1e-4f));

  // ---- L = U diag(lw) U^T row-by-row; U row i retires after L row i ----
  float L[66];
#pragma unroll
  for (int i = 0; i < 11; ++i) {
    float tk[11];
#pragma unroll
    for (int k = 0; k < 11; ++k) tk[k] = lw[k] * U[i * 11 + k];
#pragma unroll
    for (int j = i; j < 11; ++j) {
      float acc = 0.f;
#pragma unroll
      for (int k = 0; k < 11; ++k) acc = __builtin_fmaf(tk[k], U[j * 11 + k], acc);
      L[UT(i, j)] = acc;
    }
  }

  // ---- epilogue: Ws/b_lin via wave-uniform global loads (scalar cache) ----
  const float* __restrict__ wsym = ws + WS_W;
  const float* __restrict__ bl = ws + WS_B;
  float* ob = out + (size_t)b * 52;
#pragma unroll 1
  for (int c4 = 0; c4 < 13; ++c4) {
    float ov[4];
#pragma unroll
    for (int cc = 0; cc < 4; ++cc) {
      const int c = c4 * 4 + cc;
      const float* wr = wsym + c * 68;
      float a0 = 0.f, a1 = 0.f, a2 = 0.f, a3 = 0.f;
#pragma unroll
      for (int t = 0; t < 64; t += 4) {
        a0 = __builtin_fmaf(wr[t + 0], L[t + 0], a0);
        a1 = __builtin_fmaf(wr[t + 1], L[t + 1], a1);
        a2 = __builtin_fmaf(wr[t + 2], L[t + 2], a2);
        a3 = __builtin_fmaf(wr[t + 3], L[t + 3], a3);
      }
      a0 = __builtin_fmaf(wr[64], L[64], a0);
      a1 = __builtin_fmaf(wr[65], L[65], a1);
      ov[cc] = bl[c] + ((a0 + a1) + (a2 + a3));
    }
    float4 o;
    o.x = ov[0]; o.y = ov[1]; o.z = ov[2]; o.w = ov[3];
    reinterpret_cast<float4*>(ob)[c4] = o;
  }
}

extern "C" void kernel_launch(void* const* d_in, const int* in_sizes, int n_in,
                              void* d_out, int out_size, void* d_ws, size_t ws_size,
                              hipStream_t stream) {
  const float* x = (const float*)d_in[0];
  const float* w1 = (const float*)d_in[1];
  const float* w2 = (const float*)d_in[2];
  const float* wlin = (const float*)d_in[3];
  const float* blin = (const float*)d_in[4];
  float* out = (float*)d_out;
  float* ws = (float*)d_ws;  // needs 3792 floats (~15 KB)
  const int B = in_sizes[0] / 144;  // 131072
  hipLaunchKernelGGL(prep_kernel, dim3(8), dim3(256), 0, stream,
                     w1, w2, wlin, blin, ws);
  const int grid = (B + 255) / 256;
  hipLaunchKernelGGL(manifold_kernel, dim3(grid), dim3(256), 0, stream,
                     x, ws, out, B);
}

// Round 5
// 384.715 us; speedup vs baseline: 4.6579x; 4.6579x over previous
//
#include <hip/hip_runtime.h>
#include <math.h>

// SPDNet collapse: both ReEig clamps are inactive (lambda_min >= 1e-3 > 1e-4 by
// construction), so:  out = vec(logm(V^T x V)) @ w_lin^T + b_lin,  V = w1@w2.
// One thread per matrix; 11x11 Jacobi fully unrolled in registers.
//
// R5:
//  - waves_per_eu(1,1): R4's (2,2) split the file 128 VGPR + 128 AGPR and
//    scratch-spilled 6.5 GB. 1 wave/EU with 248-256 arch VGPRs is the
//    feasible operating point for the ~200-float live set.
//  - pass 2 (M = T V) fully unrolled: R3/R4 indexed T[k*12+j] by the RUNTIME
//    loop var j, demoting T to scratch (528 B/thread round-trip = the
//    "residual spill" traffic + vmcnt stalls). All-constant indices now.
//  - keep prep kernel + wave-uniform global-load epilogue (no LDS Ws).

#define NSWEEP 7

// d_ws float layout: [0..143] V (12x12, col 11 zero) | [160..211] b_lin |
//                    [256..256+52*68) Ws_sym rows padded to 68
#define WS_V 0
#define WS_B 160
#define WS_W 256

__device__ __forceinline__ constexpr int UT(int i, int j) { // i<=j, n=11 upper tri
  return i * 11 - (i * (i - 1)) / 2 + (j - i);
}

template <int P, int Q>
__device__ __forceinline__ void jrot(float (&M)[66], float (&U)[121]) {
  const float app = M[UT(P, P)];
  const float aqq = M[UT(Q, Q)];
  const float apq = M[UT(P, Q)];
  const bool tiny = __builtin_fabsf(apq) < 1e-30f;
  const float apqs = tiny ? 1.0f : apq;
  float tau = (aqq - app) * 0.5f * __builtin_amdgcn_rcpf(apqs);
  float t = __builtin_amdgcn_rcpf(__builtin_fabsf(tau) +
                                  __builtin_amdgcn_sqrtf(__builtin_fmaf(tau, tau, 1.0f)));
  t = __builtin_copysignf(t, tau);
  float c = __builtin_amdgcn_rsqf(__builtin_fmaf(t, t, 1.0f));
  float s = t * c;
  c = tiny ? 1.0f : c;
  s = tiny ? 0.0f : s;
#pragma unroll
  for (int k = 0; k < 11; ++k) {
    if (k == P || k == Q) continue;
    const int ikp = (k < P) ? UT(k, P) : UT(P, k);
    const int ikq = (k < Q) ? UT(k, Q) : UT(Q, k);
    const float akp = M[ikp], akq = M[ikq];
    M[ikp] = __builtin_fmaf(c, akp, -s * akq);
    M[ikq] = __builtin_fmaf(s, akp, c * akq);
  }
  const float cc = c * c, ss = s * s, cs2 = 2.0f * c * s * apq;
  M[UT(P, P)] = cc * app - cs2 + ss * aqq;
  M[UT(Q, Q)] = ss * app + cs2 + cc * aqq;
  M[UT(P, Q)] = 0.0f;
#pragma unroll
  for (int k = 0; k < 11; ++k) {
    const float ukp = U[k * 11 + P], ukq = U[k * 11 + Q];
    U[k * 11 + P] = __builtin_fmaf(c, ukp, -s * ukq);
    U[k * 11 + Q] = __builtin_fmaf(s, ukp, c * ukq);
  }
}

// Round-robin sweep: round R pairs { ((R+K)%11,(R+11-K)%11) }, K=1..5 ->
// 5 disjoint pairs/round (independent c,s chains -> ILP), 11 rounds = all 55.
template <int R, int K>
struct SweepRR {
  static constexpr int A0 = (R + K) % 11;
  static constexpr int B0 = (R + 11 - K) % 11;
  static constexpr int P = A0 < B0 ? A0 : B0;
  static constexpr int Q = A0 < B0 ? B0 : A0;
  static __device__ __forceinline__ void run(float (&M)[66], float (&U)[121]) {
    jrot<P, Q>(M, U);
    if constexpr (K < 5)
      SweepRR<R, K + 1>::run(M, U);
    else if constexpr (R < 10)
      SweepRR<R + 1, 1>::run(M, U);
  }
};

__global__ __launch_bounds__(256) void prep_kernel(
    const float* __restrict__ w1, const float* __restrict__ w2,
    const float* __restrict__ wlin, const float* __restrict__ blin,
    float* __restrict__ ws) {
  const int g = blockIdx.x * 256 + threadIdx.x;
  const int gs = gridDim.x * 256;
  for (int idx = g; idx < 144; idx += gs) {
    const int i = idx / 12, l = idx % 12;
    float acc = 0.f;
    if (l < 11) {
#pragma unroll
      for (int j = 0; j < 12; ++j) acc = __builtin_fmaf(w1[i * 12 + j], w2[j * 11 + l], acc);
    }
    ws[WS_V + idx] = acc;
  }
  for (int idx = g; idx < 52; idx += gs) ws[WS_B + idx] = blin[idx];
  for (int idx = g; idx < 52 * 68; idx += gs) {
    const int c = idx / 68, t = idx % 68;
    float v = 0.f;
    if (t < 66) {
      int i = 0, rem = t;
      while (rem >= 11 - i) { rem -= 11 - i; ++i; }
      const int j = i + rem;
      v = wlin[c * 121 + i * 11 + j];
      if (i != j) v += wlin[c * 121 + j * 11 + i];
    }
    ws[WS_W + idx] = v;
  }
}

__global__ __attribute__((amdgpu_flat_work_group_size(256, 256)))
__attribute__((amdgpu_waves_per_eu(1, 1)))
void manifold_kernel(const float* __restrict__ x, const float* __restrict__ ws,
                     float* __restrict__ out, int B) {
  __shared__ __align__(16) float sV[12 * 12];
  const int tid = threadIdx.x;
  if (tid < 36) {
    reinterpret_cast<float4*>(sV)[tid] =
        reinterpret_cast<const float4*>(ws + WS_V)[tid];
  }
  __syncthreads();

  const int b = blockIdx.x * 256 + tid;
  if (b >= B) return;

  // ---- Pass 1: T = V^T X (11x12), X streamed by row, V rows from LDS.
  // T indexed only by unrolled (constant) k,j -> stays in registers.
  float T[132];
#pragma unroll
  for (int e = 0; e < 132; ++e) T[e] = 0.f;
  const float4* xb4 = reinterpret_cast<const float4*>(x + (size_t)b * 144);
#pragma unroll 1
  for (int i = 0; i < 12; ++i) {
    const float4 a0 = xb4[i * 3 + 0], a1 = xb4[i * 3 + 1], a2 = xb4[i * 3 + 2];
    const float xr[12] = {a0.x, a0.y, a0.z, a0.w, a1.x, a1.y, a1.z, a1.w,
                          a2.x, a2.y, a2.z, a2.w};
    const float4 v0 = *reinterpret_cast<const float4*>(&sV[i * 12 + 0]);
    const float4 v1 = *reinterpret_cast<const float4*>(&sV[i * 12 + 4]);
    const float4 v2 = *reinterpret_cast<const float4*>(&sV[i * 12 + 8]);
    const float vr[11] = {v0.x, v0.y, v0.z, v0.w, v1.x, v1.y, v1.z, v1.w,
                          v2.x, v2.y, v2.z};
#pragma unroll
    for (int k = 0; k < 11; ++k)
#pragma unroll
      for (int j = 0; j < 12; ++j)
        T[k * 12 + j] = __builtin_fmaf(vr[k], xr[j], T[k * 12 + j]);
  }

  // ---- Pass 2: M = T V (upper triangle) — FULLY UNROLLED (constant T idx) ----
  float M[66];
#pragma unroll
  for (int e = 0; e < 66; ++e) M[e] = 0.f;
#pragma unroll
  for (int j = 0; j < 12; ++j) {
    const float4 v0 = *reinterpret_cast<const float4*>(&sV[j * 12 + 0]);
    const float4 v1 = *reinterpret_cast<const float4*>(&sV[j * 12 + 4]);
    const float4 v2 = *reinterpret_cast<const float4*>(&sV[j * 12 + 8]);
    const float vr[11] = {v0.x, v0.y, v0.z, v0.w, v1.x, v1.y, v1.z, v1.w,
                          v2.x, v2.y, v2.z};
#pragma unroll
    for (int k = 0; k < 11; ++k) {
      const float tkj = T[k * 12 + j];
#pragma unroll
      for (int l = k; l < 11; ++l)
        M[UT(k, l)] = __builtin_fmaf(tkj, vr[l], M[UT(k, l)]);
    }
  }

  // ---- Jacobi eigendecomposition (T dead from here) ----
  float U[121];
#pragma unroll
  for (int e = 0; e < 121; ++e) U[e] = 0.f;
#pragma unroll
  for (int d = 0; d < 11; ++d) U[d * 11 + d] = 1.f;
#pragma unroll 1
  for (int sweep = 0; sweep < NSWEEP; ++sweep) {
    SweepRR<0, 1>::run(M, U);
  }

  // ---- eigen-log (clamp matches the reference's preceding ReEig) ----
  float lw[11];
#pragma unroll
  for (int k = 0; k < 11; ++k) lw[k] = __logf(fmaxf(M[UT(k, k)], 1e-4f));

  // ---- L = U diag(lw) U^T row-by-row; U row i retires after L row i ----
  float L[66];
#pragma unroll
  for (int i = 0; i < 11; ++i) {
    float tk[11];
#pragma unroll
    for (int k = 0; k < 11; ++k) tk[k] = lw[k] * U[i * 11 + k];
#pragma unroll
    for (int j = i; j < 11; ++j) {
      float acc = 0.f;
#pragma unroll
      for (int k = 0; k < 11; ++k) acc = __builtin_fmaf(tk[k], U[j * 11 + k], acc);
      L[UT(i, j)] = acc;
    }
  }

  // ---- epilogue: Ws/b_lin via wave-uniform global loads (scalar cache) ----
  const float* __restrict__ wsym = ws + WS_W;
  const float* __restrict__ bl = ws + WS_B;
  float* ob = out + (size_t)b * 52;
#pragma unroll 1
  for (int c4 = 0; c4 < 13; ++c4) {
    float ov[4];
#pragma unroll
    for (int cc = 0; cc < 4; ++cc) {
      const int c = c4 * 4 + cc;
      const float* wr = wsym + c * 68;
      float a0 = 0.f, a1 = 0.f, a2 = 0.f, a3 = 0.f;
#pragma unroll
      for (int t = 0; t < 64; t += 4) {
        a0 = __builtin_fmaf(wr[t + 0], L[t + 0], a0);
        a1 = __builtin_fmaf(wr[t + 1], L[t + 1], a1);
        a2 = __builtin_fmaf(wr[t + 2], L[t + 2], a2);
        a3 = __builtin_fmaf(wr[t + 3], L[t + 3], a3);
      }
      a0 = __builtin_fmaf(wr[64], L[64], a0);
      a1 = __builtin_fmaf(wr[65], L[65], a1);
      ov[cc] = bl[c] + ((a0 + a1) + (a2 + a3));
    }
    float4 o;
    o.x = ov[0]; o.y = ov[1]; o.z = ov[2]; o.w = ov[3];
    reinterpret_cast<float4*>(ob)[c4] = o;
  }
}

extern "C" void kernel_launch(void* const* d_in, const int* in_sizes, int n_in,
                              void* d_out, int out_size, void* d_ws, size_t ws_size,
                              hipStream_t stream) {
  const float* x = (const float*)d_in[0];
  const float* w1 = (const float*)d_in[1];
  const float* w2 = (const float*)d_in[2];
  const float* wlin = (const float*)d_in[3];
  const float* blin = (const float*)d_in[4];
  float* out = (float*)d_out;
  float* ws = (float*)d_ws;  // needs 3792 floats (~15 KB)
  const int B = in_sizes[0] / 144;  // 131072
  hipLaunchKernelGGL(prep_kernel, dim3(8), dim3(256), 0, stream,
                     w1, w2, wlin, blin, ws);
  const int grid = (B + 255) / 256;
  hipLaunchKernelGGL(manifold_kernel, dim3(grid), dim3(256), 0, stream,
                     x, ws, out, B);
}

// Round 6
// 329.232 us; speedup vs baseline: 5.4429x; 1.1685x over previous
//
#include <hip/hip_runtime.h>
#include <math.h>

// SPDNet collapse: both ReEig clamps are inactive (lambda_min >= 1e-3 > 1e-4 by
// construction), so:  out = vec(logm(V^T x V)) @ w_lin^T + b_lin,  V = w1@w2.
// One thread per matrix; 11x11 Jacobi fully unrolled in registers.
//
// R6 (R5 was VALU-issue bound at 1 wave/EU, VALUBusy 66%):
//  - NSWEEP 7->6 (quadratic convergence; off-diag ~1e-10 by sweep 6).
//  - branch-free 3-trans (c,s,t) chain: t = copysign(2|apq|/(|d|+r), apq*d),
//    r = sqrt(d^2+4apq^2); +1e-30 in denom handles apq=0 (t=0,c=1,s=0) with
//    no compares. Diagonal update via app -/+ t*apq (Wilkinson form).
//  - per round: compute all 5 disjoint (c,s,t) BEFORE applying any rotation ->
//    the 5 trans chains overlap explicitly (disjoint pairs don't perturb each
//    other's app/aqq/apq; applies stay in program order for shared elements).
//  - keep: waves_per_eu(1,1), prep kernel + wave-uniform epilogue, fully
//    unrolled formation (constant indices everywhere -> no scratch demotion).

#define NSWEEP 6

// d_ws float layout: [0..143] V (12x12, col 11 zero) | [160..211] b_lin |
//                    [256..256+52*68) Ws_sym rows padded to 68
#define WS_V 0
#define WS_B 160
#define WS_W 256

__device__ __forceinline__ constexpr int UT(int i, int j) { // i<=j, n=11 upper tri
  return i * 11 - (i * (i - 1)) / 2 + (j - i);
}

template <int P, int Q>
__device__ __forceinline__ void csCompute(const float (&M)[66], float& c, float& s,
                                          float& t) {
  const float app = M[UT(P, P)], aqq = M[UT(Q, Q)], apq = M[UT(P, Q)];
  const float d2 = aqq - app;
  const float a2 = apq + apq;
  const float r = __builtin_amdgcn_sqrtf(__builtin_fmaf(d2, d2, a2 * a2));
  const float den = (__builtin_fabsf(d2) + r) + 1e-30f;
  t = __builtin_copysignf(__builtin_fabsf(a2) * __builtin_amdgcn_rcpf(den), apq * d2);
  c = __builtin_amdgcn_rsqf(__builtin_fmaf(t, t, 1.0f));
  s = t * c;
}

template <int P, int Q>
__device__ __forceinline__ void applyRot(float (&M)[66], float (&U)[121], float c,
                                         float s, float t) {
  const float apq = M[UT(P, Q)];
#pragma unroll
  for (int k = 0; k < 11; ++k) {
    if (k == P || k == Q) continue;
    const int ikp = (k < P) ? UT(k, P) : UT(P, k);
    const int ikq = (k < Q) ? UT(k, Q) : UT(Q, k);
    const float akp = M[ikp], akq = M[ikq];
    M[ikp] = __builtin_fmaf(c, akp, -s * akq);
    M[ikq] = __builtin_fmaf(s, akp, c * akq);
  }
  M[UT(P, P)] = __builtin_fmaf(-t, apq, M[UT(P, P)]);
  M[UT(Q, Q)] = __builtin_fmaf(t, apq, M[UT(Q, Q)]);
  M[UT(P, Q)] = 0.0f;
#pragma unroll
  for (int k = 0; k < 11; ++k) {
    const float ukp = U[k * 11 + P], ukq = U[k * 11 + Q];
    U[k * 11 + P] = __builtin_fmaf(c, ukp, -s * ukq);
    U[k * 11 + Q] = __builtin_fmaf(s, ukp, c * ukq);
  }
}

// Round-robin pairs: round R, K=1..5 -> 5 disjoint pairs; 11 rounds = all 55.
template <int R, int K>
struct PairRR {
  static constexpr int A0 = (R + K) % 11;
  static constexpr int B0 = (R + 11 - K) % 11;
  static constexpr int P = A0 < B0 ? A0 : B0;
  static constexpr int Q = A0 < B0 ? B0 : A0;
};

template <int R>
__device__ __forceinline__ void jround(float (&M)[66], float (&U)[121]) {
  float c1, s1, t1, c2, s2, t2, c3, s3, t3, c4, s4, t4, c5, s5, t5;
  csCompute<PairRR<R, 1>::P, PairRR<R, 1>::Q>(M, c1, s1, t1);
  csCompute<PairRR<R, 2>::P, PairRR<R, 2>::Q>(M, c2, s2, t2);
  csCompute<PairRR<R, 3>::P, PairRR<R, 3>::Q>(M, c3, s3, t3);
  csCompute<PairRR<R, 4>::P, PairRR<R, 4>::Q>(M, c4, s4, t4);
  csCompute<PairRR<R, 5>::P, PairRR<R, 5>::Q>(M, c5, s5, t5);
  applyRot<PairRR<R, 1>::P, PairRR<R, 1>::Q>(M, U, c1, s1, t1);
  applyRot<PairRR<R, 2>::P, PairRR<R, 2>::Q>(M, U, c2, s2, t2);
  applyRot<PairRR<R, 3>::P, PairRR<R, 3>::Q>(M, U, c3, s3, t3);
  applyRot<PairRR<R, 4>::P, PairRR<R, 4>::Q>(M, U, c4, s4, t4);
  applyRot<PairRR<R, 5>::P, PairRR<R, 5>::Q>(M, U, c5, s5, t5);
}

template <int R>
struct RoundSeq {
  static __device__ __forceinline__ void run(float (&M)[66], float (&U)[121]) {
    jround<R>(M, U);
    if constexpr (R < 10) RoundSeq<R + 1>::run(M, U);
  }
};

__global__ __launch_bounds__(256) void prep_kernel(
    const float* __restrict__ w1, const float* __restrict__ w2,
    const float* __restrict__ wlin, const float* __restrict__ blin,
    float* __restrict__ ws) {
  const int g = blockIdx.x * 256 + threadIdx.x;
  const int gs = gridDim.x * 256;
  for (int idx = g; idx < 144; idx += gs) {
    const int i = idx / 12, l = idx % 12;
    float acc = 0.f;
    if (l < 11) {
#pragma unroll
      for (int j = 0; j < 12; ++j) acc = __builtin_fmaf(w1[i * 12 + j], w2[j * 11 + l], acc);
    }
    ws[WS_V + idx] = acc;
  }
  for (int idx = g; idx < 52; idx += gs) ws[WS_B + idx] = blin[idx];
  for (int idx = g; idx < 52 * 68; idx += gs) {
    const int c = idx / 68, t = idx % 68;
    float v = 0.f;
    if (t < 66) {
      int i = 0, rem = t;
      while (rem >= 11 - i) { rem -= 11 - i; ++i; }
      const int j = i + rem;
      v = wlin[c * 121 + i * 11 + j];
      if (i != j) v += wlin[c * 121 + j * 11 + i];
    }
    ws[WS_W + idx] = v;
  }
}

__global__ __attribute__((amdgpu_flat_work_group_size(256, 256)))
__attribute__((amdgpu_waves_per_eu(1, 1)))
void manifold_kernel(const float* __restrict__ x, const float* __restrict__ ws,
                     float* __restrict__ out, int B) {
  __shared__ __align__(16) float sV[12 * 12];
  const int tid = threadIdx.x;
  if (tid < 36) {
    reinterpret_cast<float4*>(sV)[tid] =
        reinterpret_cast<const float4*>(ws + WS_V)[tid];
  }
  __syncthreads();

  const int b = blockIdx.x * 256 + tid;
  if (b >= B) return;

  // ---- Pass 1: T = V^T X (11x12), X streamed by row, V rows from LDS.
  float T[132];
#pragma unroll
  for (int e = 0; e < 132; ++e) T[e] = 0.f;
  const float4* xb4 = reinterpret_cast<const float4*>(x + (size_t)b * 144);
#pragma unroll 1
  for (int i = 0; i < 12; ++i) {
    const float4 a0 = xb4[i * 3 + 0], a1 = xb4[i * 3 + 1], a2 = xb4[i * 3 + 2];
    const float xr[12] = {a0.x, a0.y, a0.z, a0.w, a1.x, a1.y, a1.z, a1.w,
                          a2.x, a2.y, a2.z, a2.w};
    const float4 v0 = *reinterpret_cast<const float4*>(&sV[i * 12 + 0]);
    const float4 v1 = *reinterpret_cast<const float4*>(&sV[i * 12 + 4]);
    const float4 v2 = *reinterpret_cast<const float4*>(&sV[i * 12 + 8]);
    const float vr[11] = {v0.x, v0.y, v0.z, v0.w, v1.x, v1.y, v1.z, v1.w,
                          v2.x, v2.y, v2.z};
#pragma unroll
    for (int k = 0; k < 11; ++k)
#pragma unroll
      for (int j = 0; j < 12; ++j)
        T[k * 12 + j] = __builtin_fmaf(vr[k], xr[j], T[k * 12 + j]);
  }

  // ---- Pass 2: M = T V (upper triangle) — fully unrolled (constant T idx) ----
  float M[66];
#pragma unroll
  for (int e = 0; e < 66; ++e) M[e] = 0.f;
#pragma unroll
  for (int j = 0; j < 12; ++j) {
    const float4 v0 = *reinterpret_cast<const float4*>(&sV[j * 12 + 0]);
    const float4 v1 = *reinterpret_cast<const float4*>(&sV[j * 12 + 4]);
    const float4 v2 = *reinterpret_cast<const float4*>(&sV[j * 12 + 8]);
    const float vr[11] = {v0.x, v0.y, v0.z, v0.w, v1.x, v1.y, v1.z, v1.w,
                          v2.x, v2.y, v2.z};
#pragma unroll
    for (int k = 0; k < 11; ++k) {
      const float tkj = T[k * 12 + j];
#pragma unroll
      for (int l = k; l < 11; ++l)
        M[UT(k, l)] = __builtin_fmaf(tkj, vr[l], M[UT(k, l)]);
    }
  }

  // ---- Jacobi eigendecomposition (T dead from here) ----
  float U[121];
#pragma unroll
  for (int e = 0; e < 121; ++e) U[e] = 0.f;
#pragma unroll
  for (int d = 0; d < 11; ++d) U[d * 11 + d] = 1.f;
#pragma unroll 1
  for (int sweep = 0; sweep < NSWEEP; ++sweep) {
    RoundSeq<0>::run(M, U);
  }

  // ---- eigen-log (clamp matches the reference's preceding ReEig) ----
  float lw[11];
#pragma unroll
  for (int k = 0; k < 11; ++k) lw[k] = __logf(fmaxf(M[UT(k, k)], 1e-4f));

  // ---- L = U diag(lw) U^T row-by-row; U row i retires after L row i ----
  float L[66];
#pragma unroll
  for (int i = 0; i < 11; ++i) {
    float tk[11];
#pragma unroll
    for (int k = 0; k < 11; ++k) tk[k] = lw[k] * U[i * 11 + k];
#pragma unroll
    for (int j = i; j < 11; ++j) {
      float acc = 0.f;
#pragma unroll
      for (int k = 0; k < 11; ++k) acc = __builtin_fmaf(tk[k], U[j * 11 + k], acc);
      L[UT(i, j)] = acc;
    }
  }

  // ---- epilogue: Ws/b_lin via wave-uniform global loads (scalar cache) ----
  const float* __restrict__ wsym = ws + WS_W;
  const float* __restrict__ bl = ws + WS_B;
  float* ob = out + (size_t)b * 52;
#pragma unroll 1
  for (int c4 = 0; c4 < 13; ++c4) {
    float ov[4];
#pragma unroll
    for (int cc = 0; cc < 4; ++cc) {
      const int c = c4 * 4 + cc;
      const float* wr = wsym + c * 68;
      float a0 = 0.f, a1 = 0.f, a2 = 0.f, a3 = 0.f;
#pragma unroll
      for (int t = 0; t < 64; t += 4) {
        a0 = __builtin_fmaf(wr[t + 0], L[t + 0], a0);
        a1 = __builtin_fmaf(wr[t + 1], L[t + 1], a1);
        a2 = __builtin_fmaf(wr[t + 2], L[t + 2], a2);
        a3 = __builtin_fmaf(wr[t + 3], L[t + 3], a3);
      }
      a0 = __builtin_fmaf(wr[64], L[64], a0);
      a1 = __builtin_fmaf(wr[65], L[65], a1);
      ov[cc] = bl[c] + ((a0 + a1) + (a2 + a3));
    }
    float4 o;
    o.x = ov[0]; o.y = ov[1]; o.z = ov[2]; o.w = ov[3];
    reinterpret_cast<float4*>(ob)[c4] = o;
  }
}

extern "C" void kernel_launch(void* const* d_in, const int* in_sizes, int n_in,
                              void* d_out, int out_size, void* d_ws, size_t ws_size,
                              hipStream_t stream) {
  const float* x = (const float*)d_in[0];
  const float* w1 = (const float*)d_in[1];
  const float* w2 = (const float*)d_in[2];
  const float* wlin = (const float*)d_in[3];
  const float* blin = (const float*)d_in[4];
  float* out = (float*)d_out;
  float* ws = (float*)d_ws;  // needs 3792 floats (~15 KB)
  const int B = in_sizes[0] / 144;  // 131072
  hipLaunchKernelGGL(prep_kernel, dim3(8), dim3(256), 0, stream,
                     w1, w2, wlin, blin, ws);
  const int grid = (B + 255) / 256;
  hipLaunchKernelGGL(manifold_kernel, dim3(grid), dim3(256), 0, stream,
                     x, ws, out, B);
}

// Round 7
// 311.328 us; speedup vs baseline: 5.7559x; 1.0575x over previous
//
#include <hip/hip_runtime.h>
#include <math.h>

// SPDNet collapse: both ReEig clamps are inactive (lambda_min >= 1e-3 > 1e-4 by
// construction), so:  out = vec(logm(V^T x V)) @ w_lin^T + b_lin,  V = w1@w2.
// One thread per matrix; 11x11 Jacobi fully unrolled in registers.
//
// R7 (R6 is VALU-issue bound; dur tracks static instr count ~linearly):
//  - NSWEEP 6->5: absmax was bit-identical for 7 vs 6 sweeps -> convergence is
//    past the fp32 noise floor; 5 sweeps leaves off-diag ~1e-6||M||.
//  - shorter (c,s,t) chain: t = a2*rcp(d2 + copysign(r,d2)),
//    r = sqrt(d2^2 + a2^2 + 1e-60). copysign folds the sign logic:
//    sign(t)=sign(apq*d2); a2=0 -> t=0; d2=0 -> t=+-1 (45deg, correct).
//    ~11 instr vs ~14 per rotation.
//  - keep: waves_per_eu(1,1) [R4: 2 waves/EU = spill disaster], prep kernel +
//    wave-uniform epilogue, fully unrolled formation (constant indices only),
//    round-phase split (5 disjoint (c,s) chains computed before any apply).

#define NSWEEP 5

// d_ws float layout: [0..143] V (12x12, col 11 zero) | [160..211] b_lin |
//                    [256..256+52*68) Ws_sym rows padded to 68
#define WS_V 0
#define WS_B 160
#define WS_W 256

__device__ __forceinline__ constexpr int UT(int i, int j) { // i<=j, n=11 upper tri
  return i * 11 - (i * (i - 1)) / 2 + (j - i);
}

template <int P, int Q>
__device__ __forceinline__ void csCompute(const float (&M)[66], float& c, float& s,
                                          float& t) {
  const float app = M[UT(P, P)], aqq = M[UT(Q, Q)], apq = M[UT(P, Q)];
  const float d2 = aqq - app;
  const float a2 = apq + apq;
  const float r = __builtin_amdgcn_sqrtf(
      __builtin_fmaf(d2, d2, __builtin_fmaf(a2, a2, 1e-60f)));
  const float den = d2 + __builtin_copysignf(r, d2);
  t = a2 * __builtin_amdgcn_rcpf(den);
  c = __builtin_amdgcn_rsqf(__builtin_fmaf(t, t, 1.0f));
  s = t * c;
}

template <int P, int Q>
__device__ __forceinline__ void applyRot(float (&M)[66], float (&U)[121], float c,
                                         float s, float t) {
  const float apq = M[UT(P, Q)];
#pragma unroll
  for (int k = 0; k < 11; ++k) {
    if (k == P || k == Q) continue;
    const int ikp = (k < P) ? UT(k, P) : UT(P, k);
    const int ikq = (k < Q) ? UT(k, Q) : UT(Q, k);
    const float akp = M[ikp], akq = M[ikq];
    M[ikp] = __builtin_fmaf(c, akp, -s * akq);
    M[ikq] = __builtin_fmaf(s, akp, c * akq);
  }
  M[UT(P, P)] = __builtin_fmaf(-t, apq, M[UT(P, P)]);
  M[UT(Q, Q)] = __builtin_fmaf(t, apq, M[UT(Q, Q)]);
  M[UT(P, Q)] = 0.0f;
#pragma unroll
  for (int k = 0; k < 11; ++k) {
    const float ukp = U[k * 11 + P], ukq = U[k * 11 + Q];
    U[k * 11 + P] = __builtin_fmaf(c, ukp, -s * ukq);
    U[k * 11 + Q] = __builtin_fmaf(s, ukp, c * ukq);
  }
}

// Round-robin pairs: round R, K=1..5 -> 5 disjoint pairs; 11 rounds = all 55.
template <int R, int K>
struct PairRR {
  static constexpr int A0 = (R + K) % 11;
  static constexpr int B0 = (R + 11 - K) % 11;
  static constexpr int P = A0 < B0 ? A0 : B0;
  static constexpr int Q = A0 < B0 ? B0 : A0;
};

template <int R>
__device__ __forceinline__ void jround(float (&M)[66], float (&U)[121]) {
  float c1, s1, t1, c2, s2, t2, c3, s3, t3, c4, s4, t4, c5, s5, t5;
  csCompute<PairRR<R, 1>::P, PairRR<R, 1>::Q>(M, c1, s1, t1);
  csCompute<PairRR<R, 2>::P, PairRR<R, 2>::Q>(M, c2, s2, t2);
  csCompute<PairRR<R, 3>::P, PairRR<R, 3>::Q>(M, c3, s3, t3);
  csCompute<PairRR<R, 4>::P, PairRR<R, 4>::Q>(M, c4, s4, t4);
  csCompute<PairRR<R, 5>::P, PairRR<R, 5>::Q>(M, c5, s5, t5);
  applyRot<PairRR<R, 1>::P, PairRR<R, 1>::Q>(M, U, c1, s1, t1);
  applyRot<PairRR<R, 2>::P, PairRR<R, 2>::Q>(M, U, c2, s2, t2);
  applyRot<PairRR<R, 3>::P, PairRR<R, 3>::Q>(M, U, c3, s3, t3);
  applyRot<PairRR<R, 4>::P, PairRR<R, 4>::Q>(M, U, c4, s4, t4);
  applyRot<PairRR<R, 5>::P, PairRR<R, 5>::Q>(M, U, c5, s5, t5);
}

template <int R>
struct RoundSeq {
  static __device__ __forceinline__ void run(float (&M)[66], float (&U)[121]) {
    jround<R>(M, U);
    if constexpr (R < 10) RoundSeq<R + 1>::run(M, U);
  }
};

__global__ __launch_bounds__(256) void prep_kernel(
    const float* __restrict__ w1, const float* __restrict__ w2,
    const float* __restrict__ wlin, const float* __restrict__ blin,
    float* __restrict__ ws) {
  const int g = blockIdx.x * 256 + threadIdx.x;
  const int gs = gridDim.x * 256;
  for (int idx = g; idx < 144; idx += gs) {
    const int i = idx / 12, l = idx % 12;
    float acc = 0.f;
    if (l < 11) {
#pragma unroll
      for (int j = 0; j < 12; ++j) acc = __builtin_fmaf(w1[i * 12 + j], w2[j * 11 + l], acc);
    }
    ws[WS_V + idx] = acc;
  }
  for (int idx = g; idx < 52; idx += gs) ws[WS_B + idx] = blin[idx];
  for (int idx = g; idx < 52 * 68; idx += gs) {
    const int c = idx / 68, t = idx % 68;
    float v = 0.f;
    if (t < 66) {
      int i = 0, rem = t;
      while (rem >= 11 - i) { rem -= 11 - i; ++i; }
      const int j = i + rem;
      v = wlin[c * 121 + i * 11 + j];
      if (i != j) v += wlin[c * 121 + j * 11 + i];
    }
    ws[WS_W + idx] = v;
  }
}

__global__ __attribute__((amdgpu_flat_work_group_size(256, 256)))
__attribute__((amdgpu_waves_per_eu(1, 1)))
void manifold_kernel(const float* __restrict__ x, const float* __restrict__ ws,
                     float* __restrict__ out, int B) {
  __shared__ __align__(16) float sV[12 * 12];
  const int tid = threadIdx.x;
  if (tid < 36) {
    reinterpret_cast<float4*>(sV)[tid] =
        reinterpret_cast<const float4*>(ws + WS_V)[tid];
  }
  __syncthreads();

  const int b = blockIdx.x * 256 + tid;
  if (b >= B) return;

  // ---- Pass 1: T = V^T X (11x12), X streamed by row, V rows from LDS.
  float T[132];
#pragma unroll
  for (int e = 0; e < 132; ++e) T[e] = 0.f;
  const float4* xb4 = reinterpret_cast<const float4*>(x + (size_t)b * 144);
#pragma unroll 1
  for (int i = 0; i < 12; ++i) {
    const float4 a0 = xb4[i * 3 + 0], a1 = xb4[i * 3 + 1], a2 = xb4[i * 3 + 2];
    const float xr[12] = {a0.x, a0.y, a0.z, a0.w, a1.x, a1.y, a1.z, a1.w,
                          a2.x, a2.y, a2.z, a2.w};
    const float4 v0 = *reinterpret_cast<const float4*>(&sV[i * 12 + 0]);
    const float4 v1 = *reinterpret_cast<const float4*>(&sV[i * 12 + 4]);
    const float4 v2 = *reinterpret_cast<const float4*>(&sV[i * 12 + 8]);
    const float vr[11] = {v0.x, v0.y, v0.z, v0.w, v1.x, v1.y, v1.z, v1.w,
                          v2.x, v2.y, v2.z};
#pragma unroll
    for (int k = 0; k < 11; ++k)
#pragma unroll
      for (int j = 0; j < 12; ++j)
        T[k * 12 + j] = __builtin_fmaf(vr[k], xr[j], T[k * 12 + j]);
  }

  // ---- Pass 2: M = T V (upper triangle) — fully unrolled (constant T idx) ----
  float M[66];
#pragma unroll
  for (int e = 0; e < 66; ++e) M[e] = 0.f;
#pragma unroll
  for (int j = 0; j < 12; ++j) {
    const float4 v0 = *reinterpret_cast<const float4*>(&sV[j * 12 + 0]);
    const float4 v1 = *reinterpret_cast<const float4*>(&sV[j * 12 + 4]);
    const float4 v2 = *reinterpret_cast<const float4*>(&sV[j * 12 + 8]);
    const float vr[11] = {v0.x, v0.y, v0.z, v0.w, v1.x, v1.y, v1.z, v1.w,
                          v2.x, v2.y, v2.z};
#pragma unroll
    for (int k = 0; k < 11; ++k) {
      const float tkj = T[k * 12 + j];
#pragma unroll
      for (int l = k; l < 11; ++l)
        M[UT(k, l)] = __builtin_fmaf(tkj, vr[l], M[UT(k, l)]);
    }
  }

  // ---- Jacobi eigendecomposition (T dead from here) ----
  float U[121];
#pragma unroll
  for (int e = 0; e < 121; ++e) U[e] = 0.f;
#pragma unroll
  for (int d = 0; d < 11; ++d) U[d * 11 + d] = 1.f;
#pragma unroll 1
  for (int sweep = 0; sweep < NSWEEP; ++sweep) {
    RoundSeq<0>::run(M, U);
  }

  // ---- eigen-log (clamp matches the reference's preceding ReEig) ----
  float lw[11];
#pragma unroll
  for (int k = 0; k < 11; ++k) lw[k] = __logf(fmaxf(M[UT(k, k)], 1e-4f));

  // ---- L = U diag(lw) U^T row-by-row; U row i retires after L row i ----
  float L[66];
#pragma unroll
  for (int i = 0; i < 11; ++i) {
    float tk[11];
#pragma unroll
    for (int k = 0; k < 11; ++k) tk[k] = lw[k] * U[i * 11 + k];
#pragma unroll
    for (int j = i; j < 11; ++j) {
      float acc = 0.f;
#pragma unroll
      for (int k = 0; k < 11; ++k) acc = __builtin_fmaf(tk[k], U[j * 11 + k], acc);
      L[UT(i, j)] = acc;
    }
  }

  // ---- epilogue: Ws/b_lin via wave-uniform global loads (scalar cache) ----
  const float* __restrict__ wsym = ws + WS_W;
  const float* __restrict__ bl = ws + WS_B;
  float* ob = out + (size_t)b * 52;
#pragma unroll 1
  for (int c4 = 0; c4 < 13; ++c4) {
    float ov[4];
#pragma unroll
    for (int cc = 0; cc < 4; ++cc) {
      const int c = c4 * 4 + cc;
      const float* wr = wsym + c * 68;
      float a0 = 0.f, a1 = 0.f, a2 = 0.f, a3 = 0.f;
#pragma unroll
      for (int t = 0; t < 64; t += 4) {
        a0 = __builtin_fmaf(wr[t + 0], L[t + 0], a0);
        a1 = __builtin_fmaf(wr[t + 1], L[t + 1], a1);
        a2 = __builtin_fmaf(wr[t + 2], L[t + 2], a2);
        a3 = __builtin_fmaf(wr[t + 3], L[t + 3], a3);
      }
      a0 = __builtin_fmaf(wr[64], L[64], a0);
      a1 = __builtin_fmaf(wr[65], L[65], a1);
      ov[cc] = bl[c] + ((a0 + a1) + (a2 + a3));
    }
    float4 o;
    o.x = ov[0]; o.y = ov[1]; o.z = ov[2]; o.w = ov[3];
    reinterpret_cast<float4*>(ob)[c4] = o;
  }
}

extern "C" void kernel_launch(void* const* d_in, const int* in_sizes, int n_in,
                              void* d_out, int out_size, void* d_ws, size_t ws_size,
                              hipStream_t stream) {
  const float* x = (const float*)d_in[0];
  const float* w1 = (const float*)d_in[1];
  const float* w2 = (const float*)d_in[2];
  const float* wlin = (const float*)d_in[3];
  const float* blin = (const float*)d_in[4];
  float* out = (float*)d_out;
  float* ws = (float*)d_ws;  // needs 3792 floats (~15 KB)
  const int B = in_sizes[0] / 144;  // 131072
  hipLaunchKernelGGL(prep_kernel, dim3(8), dim3(256), 0, stream,
                     w1, w2, wlin, blin, ws);
  const int grid = (B + 255) / 256;
  hipLaunchKernelGGL(manifold_kernel, dim3(grid), dim3(256), 0, stream,
                     x, ws, out, B);
}